// Round 1
// baseline (355.040 us; speedup 1.0000x reference)
//
#include <hip/hip_runtime.h>

// LSTM_67980742362036: 2-layer LSTM (B=4096, T=200, I=32, H=6) + linear head.
// R9 = producer/consumer wave split (block = 128 = 2 waves per batch).
//  - Wave 0 (scan): clean serial loop: per step = 12 readlane + 12-FMA gates +
//    2 fused sigmoids + 4 DPP quad-broadcasts + ring ds_read prefetch. No
//    projection state, no per-step ITV==200 check (output statically peeled at
//    it=200), phantom steps 201..203 deleted. s_setprio(1).
//  - Wave 1 (producer): compact per-window projection (prologue pattern:
//    pair (2L,2L+1) owns timestep 32w+L, o-half rows), x loaded in 2x float4[4]
//    bursts to cut VGPR, written to the 64-slot ring between a barrier pair.
//  - Sync: X + 5 pairs (Y=scan left window w-2, Z=window w written). Producer
//    executes 1+5*2=11 __syncthreads, scan 1+5*2=11. Windows 5,6 need no sync
//    (written at pairs 4,5).
//  - Occupancy: LDS 9952 B -> 16 blocks/CU; 2 waves/block -> up to 32 waves/CU
//    (vs 16 in R8). Arithmetic order identical to R8 -> absmax 0 expected.

#define TLEN  200
#define ISZ   32
#define HSZ   6
#define RPITCH 25
#define WPITCH 36                      // W row pitch in dwords (bank-split fix)
#define RING_DW (64 * RPITCH)          // 1600
#define WOFF  RING_DW                  // Wih0: 24 rows x WPITCH
#define BOFF  (WOFF + 24 * WPITCH)     // bias: 24
#define LDS_DW (BOFF + 24)             // 2488 dwords = 9952 B

__device__ __forceinline__ float fast_sig(float x) {
    return __builtin_amdgcn_rcpf(1.0f + __expf(-x));   // ~1e-7 vs 3.7e-3 thr
}
__device__ __forceinline__ float rl(float v, int l) {
    return __int_as_float(__builtin_amdgcn_readlane(__float_as_int(v), l));
}
template <int CTRL>
__device__ __forceinline__ float qperm(float v) {
    return __int_as_float(__builtin_amdgcn_mov_dpp(__float_as_int(v), CTRL, 0xf, 0xf, true));
}
__device__ __forceinline__ float dot4(float4 w, float4 v) {
    return fmaf(w.x, v.x, fmaf(w.y, v.y, fmaf(w.z, v.z, w.w * v.w)));
}

__global__ __launch_bounds__(128) void lstm_one(
    const float* __restrict__ x,
    const float* __restrict__ Wih0, const float* __restrict__ Whh0,
    const float* __restrict__ bih0, const float* __restrict__ bhh0,
    const float* __restrict__ Wih1, const float* __restrict__ Whh1,
    const float* __restrict__ bih1, const float* __restrict__ bhh1,
    const float* __restrict__ Wlin, const float* __restrict__ blin,
    float* __restrict__ out)
{
    __shared__ float lds[LDS_DW];

    const int tid  = threadIdx.x;
    const int lane = tid & 63;
    const int b    = blockIdx.x;
    const float* xb = x + (size_t)b * TLEN * ISZ;

    if (tid >= 64) {
        // ================= producer wave =================
        const int o = lane & 1;
        const int L = lane >> 1;
#define LDSW(ROW, KCQ) (*(const float4*)&lds[WOFF + (o * 12 + (ROW)) * WPITCH + ((KCQ) << 2)])

        // stage Wih0 + folded bias (in-wave ordering; own use only pre-X)
#pragma unroll
        for (int k = 0; k < 13; ++k) {
            const int idx = lane + (k << 6);
            if (idx < 768) {
                const int row = idx >> 5, kk = idx & 31;
                lds[WOFF + row * WPITCH + kk] = Wih0[idx];
            } else if (idx < 792) {
                lds[BOFF + idx - 768] = bih0[idx - 768] + bhh0[idx - 768];
            }
        }

        float a0c[12];
        auto PROJW = [&](int w) {
            const int t = (w << 5) + L;
            const float4* xr4 = (const float4*)(xb + (size_t)min(t, TLEN - 1) * ISZ);
#pragma unroll
            for (int jj = 0; jj < 12; ++jj) a0c[jj] = 0.0f;
#pragma unroll
            for (int hh = 0; hh < 2; ++hh) {           // 2 half-bursts: VGPR diet
                float4 xw[4];
#pragma unroll
                for (int q = 0; q < 4; ++q) xw[q] = xr4[(hh << 2) + q];
#pragma unroll
                for (int kc = 0; kc < 4; ++kc)
#pragma unroll
                    for (int jj = 0; jj < 12; ++jj)
                        a0c[jj] += dot4(LDSW(jj, (hh << 2) + kc), xw[kc]);
            }
        };
        auto WRITEW = [&](int w) {
            const int slot = ((w << 5) + L) & 63;
#pragma unroll
            for (int jj = 0; jj < 12; ++jj) {
                float v = a0c[jj] + lds[BOFF + o * 12 + jj];
                if (jj < 6) v = (o == 1) ? v * 2.0f : v;   // g-rows 12..17 pre-x2
                lds[slot * RPITCH + o * 12 + jj] = v;
            }
        };

        PROJW(0); WRITEW(0);
        PROJW(1); WRITEW(1);
        __syncthreads();                    // X: W + ring windows 0,1 ready
#pragma unroll 1
        for (int w = 2; w < 7; ++w) {
            PROJW(w);                       // regs only: x(global) + W(LDS)
            __syncthreads();                // Y: scan finished window w-2
            WRITEW(w);                      // overwrite w-2's slots
            __syncthreads();                // Z: window w visible
        }
#undef LDSW
        return;
    }

    // ================= scan wave =================
    // lane = half*32 + 4*unit + gate(i,f,g,o)
    const bool loHalf = (lane < 32);
    const int  p  = lane & 3;
    const int  jq = (lane & 31) >> 2;
    const int  j  = (jq < HSZ) ? jq : 0;
    const int  r  = 6 * p + j;

    // scan weights (g-gate x2 pre-fold)
    float WA[6], WB[6], base1 = 0.0f, sgc = 1.0f, tgc = 0.0f;
#pragma unroll
    for (int k = 0; k < 6; ++k) { WA[k] = 0.0f; WB[k] = 0.0f; }
    if (loHalf) {
#pragma unroll
        for (int k = 0; k < 6; ++k) WA[k] = Whh0[r * 6 + k];
    } else {
#pragma unroll
        for (int k = 0; k < 6; ++k) { WA[k] = Wih1[r * 6 + k]; WB[k] = Whh1[r * 6 + k]; }
        base1 = bih1[r] + bhh1[r];
    }
    if (p == 2) {   // cell gate: tanh(g) = 2*sig(2g)-1; fold the 2g into weights
#pragma unroll
        for (int k = 0; k < 6; ++k) { WA[k] *= 2.0f; WB[k] *= 2.0f; }
        base1 *= 2.0f; sgc = 2.0f; tgc = -1.0f;
    }

    __syncthreads();                        // X: wait for ring w0,w1
    __builtin_amdgcn_s_setprio(1);          // favor the serial-chain wave

    int xoff = r;                           // ring dword offset; ^=800 per window
    float c = 0.0f, h = 0.0f;
    float xp_cur = lds[xoff];               // xp(0)

#define SCAN_STEP(XN) do { \
    const float h10 = rl(h, 0),  h11 = rl(h, 4),  h12 = rl(h, 8); \
    const float h13 = rl(h, 12), h14 = rl(h, 16), h15 = rl(h, 20); \
    const float h20 = rl(h, 32), h21 = rl(h, 36), h22 = rl(h, 40); \
    const float h23 = rl(h, 44), h24 = rl(h, 48), h25 = rl(h, 52); \
    const float _xn = (XN); \
    const float _g0 = loHalf ? xp_cur : base1; \
    const float _a0 = fmaf(WA[0], h10, fmaf(WA[2], h12, fmaf(WA[4], h14, _g0))); \
    const float _a1 = fmaf(WA[1], h11, fmaf(WA[3], h13, WA[5] * h15)); \
    const float _b0 = fmaf(WB[0], h20, fmaf(WB[2], h22, WB[4] * h24)); \
    const float _b1 = fmaf(WB[1], h21, fmaf(WB[3], h23, WB[5] * h25)); \
    const float _g  = (_a0 + _a1) + (_b0 + _b1); \
    const float _aG = fmaf(sgc, fast_sig(_g), tgc); \
    const float _iq = qperm<0x00>(_aG), _fq = qperm<0x55>(_aG); \
    const float _gq = qperm<0xAA>(_aG), _oq = qperm<0xFF>(_aG); \
    c = fmaf(_fq, c, _iq * _gq); \
    const float _th = fmaf(2.0f, fast_sig(2.0f * c), -1.0f); \
    h = _oq * _th; \
    xp_cur = _xn; \
} while (0)

    // ---- peel it=0: no h-dependency; L1 phantom stays 0 ----
    {
        const float g  = loHalf ? xp_cur : base1;
        const float aG = fmaf(sgc, fast_sig(g), tgc);
        const float iq = qperm<0x00>(aG), gq = qperm<0xAA>(aG), oq = qperm<0xFF>(aG);
        const float cn = iq * gq;                       // f*c0 = 0
        const float th = fmaf(2.0f, fast_sig(2.0f * cn), -1.0f);
        c = loHalf ? cn : 0.0f;
        h = loHalf ? (oq * th) : 0.0f;
        xp_cur = lds[xoff + RPITCH];                    // xp(1)
    }

    // ---- windows 0..5 (it 1..191), rolled: one 32-step body ----
#pragma unroll 1
    for (int w = 0; w < 6; ++w) {
        if (w > 0) SCAN_STEP(lds[xoff + RPITCH]);              // k=0
#pragma unroll
        for (int k = 1; k <= 30; ++k) SCAN_STEP(lds[xoff + (k + 1) * RPITCH]);
        xoff ^= 800;                                           // next-window base
        SCAN_STEP(lds[xoff]);                                  // k=31: cross-window prefetch
        if (w < 5) { __syncthreads(); __syncthreads(); }       // Y,Z for window w+2
    }

    // ---- tail: it 192..200 (xoff back at slots 0..31 = t 192..) ----
#pragma unroll
    for (int k = 0; k < 8; ++k) SCAN_STEP(lds[xoff + (k + 1) * RPITCH]);
    SCAN_STEP(lds[xoff + 9 * RPITCH]);                         // it=200 (prefetch unused)
    {
        float s = blin[0];
        s = fmaf(Wlin[0], rl(h, 32), s);
        s = fmaf(Wlin[1], rl(h, 36), s);
        s = fmaf(Wlin[2], rl(h, 40), s);
        s = fmaf(Wlin[3], rl(h, 44), s);
        s = fmaf(Wlin[4], rl(h, 48), s);
        s = fmaf(Wlin[5], rl(h, 52), s);
        if (lane == 0) out[b] = s;
    }
#undef SCAN_STEP
}

extern "C" void kernel_launch(void* const* d_in, const int* in_sizes, int n_in,
                              void* d_out, int out_size, void* d_ws, size_t ws_size,
                              hipStream_t stream) {
    const float* x    = (const float*)d_in[0];
    const float* Wih0 = (const float*)d_in[1];
    const float* Whh0 = (const float*)d_in[2];
    const float* bih0 = (const float*)d_in[3];
    const float* bhh0 = (const float*)d_in[4];
    const float* Wih1 = (const float*)d_in[5];
    const float* Whh1 = (const float*)d_in[6];
    const float* bih1 = (const float*)d_in[7];
    const float* bhh1 = (const float*)d_in[8];
    const float* Wlin = (const float*)d_in[9];
    const float* blin = (const float*)d_in[10];
    float* out = (float*)d_out;

    lstm_one<<<4096, 128, 0, stream>>>(x, Wih0, Whh0, bih0, bhh0,
                                       Wih1, Whh1, bih1, bhh1,
                                       Wlin, blin, out);
}

// Round 2
// 268.551 us; speedup vs baseline: 1.3221x; 1.3221x over previous
//
#include <hip/hip_runtime.h>

// LSTM_67980742362036: 2-layer LSTM (B=4096, T=200, I=32, H=6) + linear head.
// R10 = time-phase split (single wave per block, two sequential phases):
//   Phase 1: project all 200 timesteps (x @ Wih0^T + bias, g-rows pre-x2)
//            and store xp[b][t][24] to global workspace (78.6 MB, LLC-resident).
//   Phase 2: clean serial scan: per step = 1 global scalar load (4-deep
//            pipeline), 12 readlane, ~15 FMA, 2 fused sigmoids, 4 DPP.
//            No LDS ring, no spread-projection state, no per-step out-check.
// Why: R8's scan wave spent ~2/3 of its issue slots on interleaved projection
// (287 SIMD-cyc/wave-step measured vs ~100 for the pure scan). R9's wave-split
// fix failed on unified regalloc (VGPR 180 -> 2 waves/SIMD). Sequential phases
// reuse registers: VGPR = max(phase) <= 128 keeps all 16 blocks/CU resident.
// Numerics identical to R8 (same accumulation order, folding, peel) -> absmax 0.
// Fallback: if ws_size < 78.6 MB, launch the proven R8 kernel (lstm_fb).

#define TLEN  200
#define ISZ   32
#define HSZ   6
#define WPITCH 36                      // W row pitch in dwords (bank-split fix)

// ---- new-kernel LDS layout (weights + bias only) ----
#define PWOFF 0
#define PBOFF (24 * WPITCH)            // 864
#define PLDS_DW (PBOFF + 24)           // 888 dwords = 3552 B

// ---- fallback (R8) LDS layout ----
#define RPITCH 25
#define RING_DW (64 * RPITCH)          // 1600
#define FWOFF  RING_DW
#define FBOFF  (FWOFF + 24 * WPITCH)
#define FLDS_DW (FBOFF + 24)           // 2488 dwords = 9952 B

__device__ __forceinline__ float fast_sig(float x) {
    return __builtin_amdgcn_rcpf(1.0f + __expf(-x));   // ~1e-7 vs 3.7e-3 thr
}
__device__ __forceinline__ float rl(float v, int l) {
    return __int_as_float(__builtin_amdgcn_readlane(__float_as_int(v), l));
}
template <int CTRL>
__device__ __forceinline__ float qperm(float v) {
    return __int_as_float(__builtin_amdgcn_mov_dpp(__float_as_int(v), CTRL, 0xf, 0xf, true));
}
__device__ __forceinline__ float dot4(float4 w, float4 v) {
    return fmaf(w.x, v.x, fmaf(w.y, v.y, fmaf(w.z, v.z, w.w * v.w)));
}

// ======================= R10: time-phase split kernel =======================
__global__ __launch_bounds__(64) void lstm_split(
    const float* __restrict__ x,
    const float* __restrict__ Wih0, const float* __restrict__ Whh0,
    const float* __restrict__ bih0, const float* __restrict__ bhh0,
    const float* __restrict__ Wih1, const float* __restrict__ Whh1,
    const float* __restrict__ bih1, const float* __restrict__ bhh1,
    const float* __restrict__ Wlin, const float* __restrict__ blin,
    float* __restrict__ out, float* __restrict__ xp)
{
    __shared__ float lds[PLDS_DW];

    const int lane = threadIdx.x;
    const int b    = blockIdx.x;
    const float* xb  = x  + (size_t)b * TLEN * ISZ;
    float*       xpb = xp + (size_t)b * TLEN * 24;

    // ================= phase 1: projection -> workspace =================
    {
        const int o = lane & 1;          // pair (2L,2L+1) owns timestep; o = row half
        const int L = lane >> 1;
#define LDSW(ROW, KCQ) (*(const float4*)&lds[PWOFF + (o * 12 + (ROW)) * WPITCH + ((KCQ) << 2)])

        // stage Wih0 + folded bias (single wave: in-wave ordering, no barrier)
#pragma unroll
        for (int k = 0; k < 13; ++k) {
            const int idx = lane + (k << 6);
            if (idx < 768) {
                const int row = idx >> 5, kk = idx & 31;
                lds[PWOFF + row * WPITCH + kk] = Wih0[idx];
            } else if (idx < 792) {
                lds[PBOFF + idx - 768] = bih0[idx - 768] + bhh0[idx - 768];
            }
        }

#pragma unroll 1
        for (int k7 = 0; k7 < 7; ++k7) {
            const int t = (k7 << 5) + L;
            if (t < TLEN) {
                const float4* xr4 = (const float4*)(xb + (size_t)t * ISZ);
                float a0c[12];
#pragma unroll
                for (int jj = 0; jj < 12; ++jj) a0c[jj] = 0.0f;
                // per-element accumulation order = kc ascending 0..7 (matches R8)
#pragma unroll
                for (int hh = 0; hh < 2; ++hh) {       // x in 2 half-bursts (VGPR cap)
                    float4 xw[4];
#pragma unroll
                    for (int q = 0; q < 4; ++q) xw[q] = xr4[(hh << 2) + q];
#pragma unroll
                    for (int jh = 0; jh < 2; ++jh)     // W-row chunking (VGPR cap)
#pragma unroll
                        for (int kc = 0; kc < 4; ++kc)
#pragma unroll
                            for (int jj = jh * 6; jj < jh * 6 + 6; ++jj)
                                a0c[jj] += dot4(LDSW(jj, (hh << 2) + kc), xw[kc]);
                }
                float vv[12];
#pragma unroll
                for (int jj = 0; jj < 12; ++jj) {
                    float v = a0c[jj] + lds[PBOFF + o * 12 + jj];
                    if (jj < 6) v = (o == 1) ? v * 2.0f : v;   // g-rows 12..17 pre-x2
                    vv[jj] = v;
                }
                float4* dst = (float4*)(xpb + t * 24 + o * 12);
                dst[0] = make_float4(vv[0], vv[1], vv[2],  vv[3]);
                dst[1] = make_float4(vv[4], vv[5], vv[6],  vv[7]);
                dst[2] = make_float4(vv[8], vv[9], vv[10], vv[11]);
            }
        }
#undef LDSW
    }

    // drain own stores before reading them back (same-wave global RAW)
    asm volatile("s_waitcnt vmcnt(0)" ::: "memory");

    // ================= phase 2: clean scan =================
    // lane = half*32 + 4*unit + gate(i,f,g,o)
    const bool loHalf = (lane < 32);
    const int  p  = lane & 3;
    const int  jq = (lane & 31) >> 2;
    const int  j  = (jq < HSZ) ? jq : 0;
    const int  r  = 6 * p + j;

    // scan weights (g-gate x2 pre-fold) — identical to R8
    float WA[6], WB[6], base1 = 0.0f, sgc = 1.0f, tgc = 0.0f;
#pragma unroll
    for (int k = 0; k < 6; ++k) { WA[k] = 0.0f; WB[k] = 0.0f; }
    if (loHalf) {
#pragma unroll
        for (int k = 0; k < 6; ++k) WA[k] = Whh0[r * 6 + k];
    } else {
#pragma unroll
        for (int k = 0; k < 6; ++k) { WA[k] = Wih1[r * 6 + k]; WB[k] = Whh1[r * 6 + k]; }
        base1 = bih1[r] + bhh1[r];
    }
    if (p == 2) {   // cell gate: tanh(g) = 2*sig(2g)-1; fold the 2g into weights
#pragma unroll
        for (int k = 0; k < 6; ++k) { WA[k] *= 2.0f; WB[k] *= 2.0f; }
        base1 *= 2.0f; sgc = 2.0f; tgc = -1.0f;
    }

    // xp pipeline: depth-4 rotating prefetch of xp[t][r]
    const float* xr = xpb + r;                 // row stride = 24 floats
    float xp0 = xr[0];
    float q0 = xr[24], q1 = xr[48], q2 = xr[72], q3 = xr[96];   // xp(1..4)

    float c = 0.0f, h = 0.0f;

#define SSTEP(XPV) do { \
    const float h10 = rl(h, 0),  h11 = rl(h, 4),  h12 = rl(h, 8); \
    const float h13 = rl(h, 12), h14 = rl(h, 16), h15 = rl(h, 20); \
    const float h20 = rl(h, 32), h21 = rl(h, 36), h22 = rl(h, 40); \
    const float h23 = rl(h, 44), h24 = rl(h, 48), h25 = rl(h, 52); \
    const float _g0 = loHalf ? (XPV) : base1; \
    const float _a0 = fmaf(WA[0], h10, fmaf(WA[2], h12, fmaf(WA[4], h14, _g0))); \
    const float _a1 = fmaf(WA[1], h11, fmaf(WA[3], h13, WA[5] * h15)); \
    const float _b0 = fmaf(WB[0], h20, fmaf(WB[2], h22, WB[4] * h24)); \
    const float _b1 = fmaf(WB[1], h21, fmaf(WB[3], h23, WB[5] * h25)); \
    const float _g  = (_a0 + _a1) + (_b0 + _b1); \
    const float _aG = fmaf(sgc, fast_sig(_g), tgc); \
    const float _iq = qperm<0x00>(_aG), _fq = qperm<0x55>(_aG); \
    const float _gq = qperm<0xAA>(_aG), _oq = qperm<0xFF>(_aG); \
    c = fmaf(_fq, c, _iq * _gq); \
    const float _th = fmaf(2.0f, fast_sig(2.0f * c), -1.0f); \
    h = _oq * _th; \
} while (0)

    // ---- peel it=0: no h-dependency; L1 phantom stays 0 (identical to R8) ----
    {
        const float g  = loHalf ? xp0 : base1;
        const float aG = fmaf(sgc, fast_sig(g), tgc);
        const float iq = qperm<0x00>(aG), gq = qperm<0xAA>(aG), oq = qperm<0xFF>(aG);
        const float cn = iq * gq;                       // f*c0 = 0
        const float th = fmaf(2.0f, fast_sig(2.0f * cn), -1.0f);
        c = loHalf ? cn : 0.0f;
        h = loHalf ? (oq * th) : 0.0f;
    }

    // ---- it = 1..192: 24 bodies x 8 steps, depth-4 prefetch ----
    const float* P = xr + 24;                  // row of it=1
#pragma unroll 1
    for (int bod = 0; bod < 24; ++bod) {
        SSTEP(q0); q0 = P[4 * 24];
        SSTEP(q1); q1 = P[5 * 24];
        SSTEP(q2); q2 = P[6 * 24];
        SSTEP(q3); q3 = P[7 * 24];
        SSTEP(q0); q0 = P[8 * 24];
        SSTEP(q1); q1 = P[9 * 24];
        SSTEP(q2); q2 = P[10 * 24];
        SSTEP(q3); q3 = P[11 * 24];
        P += 8 * 24;
    }
    // ---- tail: it = 193..200 (P at row 193; prefetch clamped to row 199) ----
    SSTEP(q0); q0 = P[4 * 24];                 // load xp(197)
    SSTEP(q1); q1 = P[5 * 24];                 // load xp(198)
    SSTEP(q2); q2 = P[6 * 24];                 // load xp(199)
    SSTEP(q3);                                 // it=196
    SSTEP(q0);                                 // it=197
    SSTEP(q1);                                 // it=198
    SSTEP(q2);                                 // it=199
    SSTEP(q3);                                 // it=200 (lo-half xp stale: finite, unused)
    {
        float s = blin[0];
        s = fmaf(Wlin[0], rl(h, 32), s);
        s = fmaf(Wlin[1], rl(h, 36), s);
        s = fmaf(Wlin[2], rl(h, 40), s);
        s = fmaf(Wlin[3], rl(h, 44), s);
        s = fmaf(Wlin[4], rl(h, 48), s);
        s = fmaf(Wlin[5], rl(h, 52), s);
        if (lane == 0) out[b] = s;
    }
#undef SSTEP
}

// ======================= fallback: proven R8 kernel (135.5 us) =======================
__global__ __launch_bounds__(64) void lstm_fb(
    const float* __restrict__ x,
    const float* __restrict__ Wih0, const float* __restrict__ Whh0,
    const float* __restrict__ bih0, const float* __restrict__ bhh0,
    const float* __restrict__ Wih1, const float* __restrict__ Whh1,
    const float* __restrict__ bih1, const float* __restrict__ bhh1,
    const float* __restrict__ Wlin, const float* __restrict__ blin,
    float* __restrict__ out)
{
    __shared__ float lds[FLDS_DW];

    const int lane = threadIdx.x;
    const int b    = blockIdx.x;

    const int o = lane & 1;
    const int L = lane >> 1;

    const bool loHalf = (lane < 32);
    const int  p  = lane & 3;
    const int  jq = (lane & 31) >> 2;
    const int  j  = (jq < HSZ) ? jq : 0;
    const int  r  = 6 * p + j;

#define LDSW(ROW, KCQ) (*(const float4*)&lds[FWOFF + (o * 12 + (ROW)) * WPITCH + ((KCQ) << 2)])

#pragma unroll
    for (int k = 0; k < 13; ++k) {
        const int idx = lane + (k << 6);
        if (idx < 768) {
            const int row = idx >> 5, kk = idx & 31;
            lds[FWOFF + row * WPITCH + kk] = Wih0[idx];
        } else if (idx < 792) {
            lds[FBOFF + idx - 768] = bih0[idx - 768] + bhh0[idx - 768];
        }
    }

    float WA[6], WB[6], base1 = 0.0f, sgc = 1.0f, tgc = 0.0f;
#pragma unroll
    for (int k = 0; k < 6; ++k) { WA[k] = 0.0f; WB[k] = 0.0f; }
    if (loHalf) {
#pragma unroll
        for (int k = 0; k < 6; ++k) WA[k] = Whh0[r * 6 + k];
    } else {
#pragma unroll
        for (int k = 0; k < 6; ++k) { WA[k] = Wih1[r * 6 + k]; WB[k] = Whh1[r * 6 + k]; }
        base1 = bih1[r] + bhh1[r];
    }
    if (p == 2) {
#pragma unroll
        for (int k = 0; k < 6; ++k) { WA[k] *= 2.0f; WB[k] *= 2.0f; }
        base1 *= 2.0f; sgc = 2.0f; tgc = -1.0f;
    }

    const float* xb = x + (size_t)b * TLEN * ISZ;

#pragma unroll
    for (int w01 = 0; w01 < 2; ++w01) {
        const int t = (w01 << 5) + L;
        const float4* xr4 = (const float4*)(xb + t * ISZ);
        float4 xw[8];
#pragma unroll
        for (int q = 0; q < 8; ++q) xw[q] = xr4[q];
        float a0c[12];
#pragma unroll
        for (int jj = 0; jj < 12; ++jj) a0c[jj] = 0.0f;
#pragma unroll
        for (int kc = 0; kc < 8; ++kc)
#pragma unroll
            for (int jj = 0; jj < 12; ++jj)
                a0c[jj] += dot4(LDSW(jj, kc), xw[kc]);
#pragma unroll
        for (int jj = 0; jj < 12; ++jj) {
            float v = a0c[jj] + lds[FBOFF + o * 12 + jj];
            if (jj < 6) v = (o == 1) ? v * 2.0f : v;
            lds[t * RPITCH + o * 12 + jj] = v;
        }
    }

    float acc[12];
#pragma unroll
    for (int jj = 0; jj < 12; ++jj) acc[jj] = 0.0f;
    const float* pc = xb + (size_t)min(64 + L, TLEN - 1) * ISZ;
    const float* pn = xb + (size_t)min(96 + L, TLEN - 1) * ISZ;
    float4 f0, f1;
    f1 = *((const float4*)pc);
    float4 Wp0 = LDSW(0, 0), Wp1 = LDSW(1, 0), Wp2 = LDSW(2, 0);

    float c = 0.0f, h = 0.0f;
    float xp_cur = lds[r];

#define KC_HEAD(KC) do { \
    f0 = f1; \
    const float4* _srcp = ((KC) < 7) ? ((const float4*)pc + (KC) + 1) \
                                     : ((const float4*)pn); \
    f1 = *_srcp; \
} while (0)

#define SPREAD_STEP(RT, KC) do { \
    acc[3*(RT)+0] += dot4(Wp0, f0); \
    acc[3*(RT)+1] += dot4(Wp1, f0); \
    acc[3*(RT)+2] += dot4(Wp2, f0); \
    const int _rtn = ((RT) + 1) & 3; \
    const int _kcn = ((RT) == 3) ? (((KC) + 1) & 7) : (KC); \
    Wp0 = LDSW(3*_rtn + 0, _kcn); \
    Wp1 = LDSW(3*_rtn + 1, _kcn); \
    Wp2 = LDSW(3*_rtn + 2, _kcn); \
} while (0)

#define SCAN_STEP(ITV) do { \
    const float h10=rl(h,0),  h11=rl(h,4),  h12=rl(h,8); \
    const float h13=rl(h,12), h14=rl(h,16), h15=rl(h,20); \
    const float h20=rl(h,32), h21=rl(h,36), h22=rl(h,40); \
    const float h23=rl(h,44), h24=rl(h,48), h25=rl(h,52); \
    const float _xn = lds[(((ITV) + 1) & 63) * RPITCH + r]; \
    const float _g0 = loHalf ? xp_cur : base1; \
    const float _a0 = fmaf(WA[0],h10, fmaf(WA[2],h12, fmaf(WA[4],h14, _g0))); \
    const float _a1 = fmaf(WA[1],h11, fmaf(WA[3],h13, WA[5]*h15)); \
    const float _b0 = fmaf(WB[0],h20, fmaf(WB[2],h22, WB[4]*h24)); \
    const float _b1 = fmaf(WB[1],h21, fmaf(WB[3],h23, WB[5]*h25)); \
    const float _g  = (_a0 + _a1) + (_b0 + _b1); \
    const float _aG = fmaf(sgc, fast_sig(_g), tgc); \
    const float _iq = qperm<0x00>(_aG), _fq = qperm<0x55>(_aG); \
    const float _gq = qperm<0xAA>(_aG), _oq = qperm<0xFF>(_aG); \
    c = fmaf(_fq, c, _iq * _gq); \
    const float _th = fmaf(2.0f, fast_sig(2.0f * c), -1.0f); \
    h = _oq * _th; \
    xp_cur = _xn; \
    if ((ITV) == 200) { \
        float _s = blin[0]; \
        _s = fmaf(Wlin[0], rl(h, 32), _s); \
        _s = fmaf(Wlin[1], rl(h, 36), _s); \
        _s = fmaf(Wlin[2], rl(h, 40), _s); \
        _s = fmaf(Wlin[3], rl(h, 44), _s); \
        _s = fmaf(Wlin[4], rl(h, 48), _s); \
        _s = fmaf(Wlin[5], rl(h, 52), _s); \
        if (lane == 0) out[b] = _s; \
    } \
} while (0)

#define ENTRY(IT0) do { \
    const int _slot = ((IT0) + 32 + L) & 63; \
    _Pragma("unroll") \
    for (int _jj = 0; _jj < 12; ++_jj) { \
        float _v = acc[_jj] + lds[FBOFF + o * 12 + _jj]; \
        if (_jj < 6) _v = (o == 1) ? _v * 2.0f : _v; \
        lds[_slot * RPITCH + o * 12 + _jj] = _v; \
        acc[_jj] = 0.0f; \
    } \
    pc = pn; \
    pn = xb + (size_t)min((IT0) + 96 + L, TLEN - 1) * ISZ; \
} while (0)

    KC_HEAD(0);
    SPREAD_STEP(0, 0);
    {
        const float g  = loHalf ? xp_cur : base1;
        const float aG = fmaf(sgc, fast_sig(g), tgc);
        const float iq = qperm<0x00>(aG), gq = qperm<0xAA>(aG), oq = qperm<0xFF>(aG);
        const float cn = iq * gq;
        const float th = fmaf(2.0f, fast_sig(2.0f * cn), -1.0f);
        c = loHalf ? cn : 0.0f;
        h = loHalf ? (oq * th) : 0.0f;
        xp_cur = lds[RPITCH + r];
    }

    SPREAD_STEP(1, 0); SCAN_STEP(1);
    SPREAD_STEP(2, 0); SCAN_STEP(2);
    SPREAD_STEP(3, 0); SCAN_STEP(3);
    for (int kc = 1; kc < 8; ++kc) {
        KC_HEAD(kc);
        const int itb = kc << 2;
        SPREAD_STEP(0, kc); SCAN_STEP(itb + 0);
        SPREAD_STEP(1, kc); SCAN_STEP(itb + 1);
        SPREAD_STEP(2, kc); SCAN_STEP(itb + 2);
        SPREAD_STEP(3, kc); SCAN_STEP(itb + 3);
    }

    for (int w = 1; w < 7; ++w) {
        const int it0 = w << 5;
        ENTRY(it0);
        for (int kc = 0; kc < 8; ++kc) {
            const int itb = it0 + (kc << 2);
            if (itb > 200) break;
            KC_HEAD(kc);
            SPREAD_STEP(0, kc); SCAN_STEP(itb + 0);
            SPREAD_STEP(1, kc); SCAN_STEP(itb + 1);
            SPREAD_STEP(2, kc); SCAN_STEP(itb + 2);
            SPREAD_STEP(3, kc); SCAN_STEP(itb + 3);
        }
    }

#undef LDSW
#undef KC_HEAD
#undef SPREAD_STEP
#undef SCAN_STEP
#undef ENTRY
}

extern "C" void kernel_launch(void* const* d_in, const int* in_sizes, int n_in,
                              void* d_out, int out_size, void* d_ws, size_t ws_size,
                              hipStream_t stream) {
    const float* x    = (const float*)d_in[0];
    const float* Wih0 = (const float*)d_in[1];
    const float* Whh0 = (const float*)d_in[2];
    const float* bih0 = (const float*)d_in[3];
    const float* bhh0 = (const float*)d_in[4];
    const float* Wih1 = (const float*)d_in[5];
    const float* Whh1 = (const float*)d_in[6];
    const float* bih1 = (const float*)d_in[7];
    const float* bhh1 = (const float*)d_in[8];
    const float* Wlin = (const float*)d_in[9];
    const float* blin = (const float*)d_in[10];
    float* out = (float*)d_out;

    const size_t XP_BYTES = (size_t)4096 * TLEN * 24 * sizeof(float);  // 78.6 MB
    if (d_ws != nullptr && ws_size >= XP_BYTES) {
        lstm_split<<<4096, 64, 0, stream>>>(x, Wih0, Whh0, bih0, bhh0,
                                            Wih1, Whh1, bih1, bhh1,
                                            Wlin, blin, out, (float*)d_ws);
    } else {
        lstm_fb<<<4096, 64, 0, stream>>>(x, Wih0, Whh0, bih0, bhh0,
                                         Wih1, Whh1, bih1, bhh1,
                                         Wlin, blin, out);
    }
}